// Round 15
// baseline (727.855 us; speedup 1.0000x reference)
//
#include <hip/hip_runtime.h>
#include <math.h>

// clDice loss on MI355X (gfx950).
// soft_skeletonize = 20 iterations of:
//   m = minpool3(x); contour = relu(maxpool3(m) - m); x = relu(x - contour)
// Round-25: z-pair ILP probe. Ledger: r14 (K=4/BH=64/(256,1)) = 559.6us,
// VGPR=64 (no clamp, no spills); rate ladder 0.49/0.51/0.72 us per
// block-iter at 8/4/2 blocks/CU -> BH=64's 2 blocks/CU exposes per-iter
// latency (LDS ~120cyc + pk chains + 2 barriers) that TLP used to hide.
// This round fills those stalls from WITHIN the wave: each block
// processes pred_i AND gt_i (identical y-geometry -> masks, addresses,
// band logic shared; two fully independent data paths -> 2x ILP).
// Grid 256 blocks (16 bands x 16 pairs) = 1 block/CU, 4 waves. State
// ~160-200 VGPR; (256,1) budget covers (r13's lever finally pays).
// Gates: VGPR > 128 AND FETCH ~91MB (ballooning = spills = abort).
// Predicted: ~90-110us/launch, total ~460-530, VALUBusy 55-70%,
// Occupancy ~8% (expected at 4 waves/CU, not a failure).
// Failure: >=130us/launch -> ILP can't replace TLP -> revert r14, try
// BH=32+z-pair (2 blocks/CU + ILP) as final combo.
// Engine per image unchanged: BH=64, K=4, single-buffered edges,
// 2 barriers/iter, unroll-4, interior-band mask elision, prefetch,
// 5 launches + finalize, partials over A (launch 5 reads B).

#define IMG_H 1024
#define IMG_W 1024
#define IMG_N (IMG_H * IMG_W)
#define NIMG  16
#define NZ    32                    // 16 pred + 16 gt images
#define BH    64                    // output rows per band
#define NBANDS (IMG_H / BH)         // 16
#define K     4                     // fused skeleton iterations per launch
#define EW    258                   // 256 lanes + 2 guard slots
#define NPART (NZ * NBANDS)         // 512 partial pairs (2 per block)
#define NITER (BH + 6 * K)          // 88 row-iterations

typedef _Float16 h2 __attribute__((ext_vector_type(2)));

__device__ __forceinline__ h2 hmin2(h2 a, h2 b) { return __builtin_elementwise_min(a, b); }
__device__ __forceinline__ h2 hmax2(h2 a, h2 b) { return __builtin_elementwise_max(a, b); }

union U32H { unsigned u; h2 h; };
__device__ __forceinline__ unsigned as_u(h2 h) { U32H t; t.h = h; return t.u; }
__device__ __forceinline__ h2 as_h2(unsigned u) { U32H t; t.u = u; return t.h; }

struct Hp { h2 lo, hi; };           // 4 image columns per lane
struct St { Hp hm1, hm2, m2, m3, q1, q2, x1, x2, x3, xc; };

// One pipeline stage. rmask: +inf pass / -inf force (maxpool row padding);
// only applied when MASKED (edge bands). Edge pair layout:
// e2[slot].x = {x_col0, m_col0} (read by LEFT-seeking neighbor at t+2);
// e2[slot].y = {x_col3, m_col3} (read at slot t). Single-buffered: caller
// guarantees barriers between prev writes / these reads / next writes.
template<int MASKED>
__device__ __forceinline__ Hp stage_step(
    St& s, h2 rmask, int t, const uint2 (&e2)[EW])
{
    h2 lp = as_h2(e2[t].y);        // left nbr's col3 {x, m}
    h2 rp = as_h2(e2[t + 2].x);    // right nbr's col0 {x, m}
    // h-min3 of x row
    h2 midx = (h2){s.xc.lo[1], s.xc.hi[0]};               // {x1, x2}
    h2 hlo = hmin2(hmin2((h2){lp[0], s.xc.lo[0]}, s.xc.lo), midx);
    h2 hhi = hmin2(hmin2(midx, s.xc.hi), (h2){s.xc.hi[1], rp[0]});
    // v-min3 (+ row-validity mask on edge bands only)
    h2 mlo, mhi;
    if constexpr (MASKED) {
        mlo = hmin2(hmin2(hmin2(s.hm1.lo, s.hm2.lo), hlo), rmask);
        mhi = hmin2(hmin2(hmin2(s.hm1.hi, s.hm2.hi), hhi), rmask);
    } else {
        mlo = hmin2(hmin2(s.hm1.lo, s.hm2.lo), hlo);
        mhi = hmin2(hmin2(s.hm1.hi, s.hm2.hi), hhi);
    }
    // h-max3 of m (previous iter's m, in m2; neighbor edges from LDS)
    h2 midm = (h2){s.m2.lo[1], s.m2.hi[0]};
    h2 qlo = hmax2(hmax2((h2){lp[1], s.m2.lo[0]}, s.m2.lo), midm);
    h2 qhi = hmax2(hmax2(midm, s.m2.hi), (h2){s.m2.hi[1], rp[1]});
    // v-max3
    h2 Mlo = hmax2(hmax2(s.q1.lo, s.q2.lo), qlo);
    h2 Mhi = hmax2(hmax2(s.q1.hi, s.q2.hi), qhi);
    // contour + relu update
    const h2 Z2 = (h2){(_Float16)0.f, (_Float16)0.f};
    h2 elo = hmax2(s.x3.lo - hmax2(Mlo - s.m3.lo, Z2), Z2);
    h2 ehi = hmax2(s.x3.hi - hmax2(Mhi - s.m3.hi, Z2), Z2);
    // ring shifts
    s.hm1 = s.hm2; s.hm2.lo = hlo; s.hm2.hi = hhi;
    s.m3  = s.m2;  s.m2.lo  = mlo; s.m2.hi  = mhi;
    s.q1  = s.q2;  s.q2.lo  = qlo; s.q2.hi  = qhi;
    s.x3  = s.x2;  s.x2 = s.x1;    s.x1 = s.xc;
    Hp e; e.lo = elo; e.hi = ehi;
    return e;
}

// Load one input row. MASKED: +inf outside the image. Unmasked (interior
// bands): every touched row is provably in-bounds -> unconditional load.
template<int FIRST, int MASKED>
__device__ __forceinline__ Hp load_row(
    int y, int c, const float* __restrict__ f32src,
    const unsigned short* __restrict__ bsrc)
{
    const _Float16 HINF = (_Float16)__builtin_huge_valf();
    Hp x; x.lo = (h2){HINF, HINF}; x.hi = (h2){HINF, HINF};
    if (!MASKED || (unsigned)y < (unsigned)IMG_H) {
        if constexpr (FIRST) {
            float4 f = *(const float4*)(f32src + (size_t)y * IMG_W + c);
            x.lo = (h2){(_Float16)f.x, (_Float16)f.y};
            x.hi = (h2){(_Float16)f.z, (_Float16)f.w};
        } else {
            uint2 u = *(const uint2*)(bsrc + (size_t)y * IMG_W + c);
            x.lo = as_h2(u.x);
            x.hi = as_h2(u.y);
        }
    }
    return x;
}

template<int FIRST, int LAST, int MASKED>
__device__ __forceinline__ void iter_step(
    int y, int t, int c, int r0, St (&st)[2][K], Hp (&xn)[2],
    const float* const (&f32src)[2], const unsigned short* const (&bsrc)[2],
    unsigned short* const (&bdst)[2], const float* const (&oth)[2],
    float (&acc)[4], uint2 (&e2)[2][K][EW])
{
    const _Float16 HINF = (_Float16)__builtin_huge_valf();
    const h2 PINF2 = (h2){HINF, HINF};
    const h2 NINF2 = (h2){-HINF, -HINF};

    // issue both row-(y+2) loads now; consumed NEXT iteration.
    Hp tnext[2];
    #pragma unroll
    for (int im = 0; im < 2; ++im)
        tnext[im] = load_row<FIRST, MASKED>(y + 2, c, f32src[im], bsrc[im]);

    __syncthreads();                         // prev-iter edge writes visible

    Hp eK[2];
    #pragma unroll
    for (int im = 0; im < 2; ++im) {
        h2 rm = PINF2;
        if constexpr (MASKED)
            rm = ((unsigned)(y - (4 * (K - 1) + 1)) < (unsigned)IMG_H) ? PINF2 : NINF2;
        eK[im] = stage_step<MASKED>(st[im][K - 1], rm, t, e2[im][K - 1]);
        #pragma unroll
        for (int k = K - 2; k >= 0; --k) {
            if constexpr (MASKED)
                rm = ((unsigned)(y - 4 * k - 1) < (unsigned)IMG_H) ? PINF2 : NINF2;
            Hp e = stage_step<MASKED>(st[im][k], rm, t, e2[im][k]);
            if constexpr (MASKED) {
                h2 em = ((unsigned)(y - 4 * k - 3) < (unsigned)IMG_H) ? NINF2 : PINF2;
                st[im][k + 1].xc.lo = hmax2(e.lo, em);
                st[im][k + 1].xc.hi = hmax2(e.hi, em);
            } else {
                st[im][k + 1].xc = e;
            }
        }
        st[im][0].xc = xn[im];               // row y+1, loaded last iteration
        xn[im] = tnext[im];
    }

    __syncthreads();                         // all edge reads done

    // edge writes for next iteration (new xc + this iter's m, now in m2)
    #pragma unroll
    for (int im = 0; im < 2; ++im)
        #pragma unroll
        for (int k = 0; k < K; ++k)
            e2[im][k][t + 1] = make_uint2(
                as_u((h2){st[im][k].xc.lo[0], st[im][k].m2.lo[0]}),
                as_u((h2){st[im][k].xc.hi[1], st[im][k].m2.hi[1]}));

    int orow = y - (4 * (K - 1) + 3);        // y - 15
    if ((unsigned)(orow - r0) < (unsigned)BH) {
        #pragma unroll
        for (int im = 0; im < 2; ++im) {
            if constexpr (!LAST) {
                *(uint2*)(bdst[im] + (size_t)orow * IMG_W + c) =
                    make_uint2(as_u(eK[im].lo), as_u(eK[im].hi));
            } else {
                float4 ov = *(const float4*)(oth[im] + (size_t)orow * IMG_W + c);
                float e0 = (float)eK[im].lo[0], e1 = (float)eK[im].lo[1];
                float e2f = (float)eK[im].hi[0], e3 = (float)eK[im].hi[1];
                acc[2 * im]     += e0 * ov.x + e1 * ov.y + e2f * ov.z + e3 * ov.w;
                acc[2 * im + 1] += e0 + e1 + e2f + e3;
            }
        }
    }
}

template<int FIRST, int LAST>
__global__ __launch_bounds__(256, 1) void skel(
    const unsigned short* __restrict__ src, unsigned short* __restrict__ dst,
    const float* __restrict__ pred32, const float* __restrict__ gt32,
    double* __restrict__ partials)
{
    __shared__ uint2 e2[2][K][EW];    // per-image single-buffered edges
    __shared__ double lsum[4][4];     // [quantity][wave]

    const int t = threadIdx.x, c = 4 * t;
    const int band = blockIdx.x, z = blockIdx.y;   // z in [0, NIMG)
    const int r0 = band * BH;
    const _Float16 HINF = (_Float16)__builtin_huge_valf();
    const h2 PINF2 = (h2){HINF, HINF};
    const h2 NINF2 = (h2){-HINF, -HINF};

    // image 0 = pred_z (skel dotted with gt_z); image 1 = gt_z (with pred_z)
    const float* f32src[2] = { pred32 + (size_t)z * IMG_N,
                               gt32   + (size_t)z * IMG_N };
    const unsigned short* bsrc[2] = {
        FIRST ? nullptr : src + (size_t)z * IMG_N,
        FIRST ? nullptr : src + (size_t)(z + NIMG) * IMG_N };
    unsigned short* bdst[2] = {
        LAST ? nullptr : dst + (size_t)z * IMG_N,
        LAST ? nullptr : dst + (size_t)(z + NIMG) * IMG_N };
    const float* oth[2] = {
        LAST ? gt32   + (size_t)z * IMG_N : nullptr,
        LAST ? pred32 + (size_t)z * IMG_N : nullptr };

    if (t < K) {
        #pragma unroll
        for (int im = 0; im < 2; ++im) {
            // guard pairs: x=+inf (0x7C00 low), m=-inf (0xFC00 high)
            e2[im][t][0]      = make_uint2(0u, 0xFC007C00u);  // only .y read
            e2[im][t][EW - 1] = make_uint2(0xFC007C00u, 0u);  // only .x read
        }
    }

    St st[2][K];
    #pragma unroll
    for (int im = 0; im < 2; ++im)
        #pragma unroll
        for (int k = 0; k < K; ++k) {
            st[im][k].hm1.lo = st[im][k].hm1.hi = PINF2;
            st[im][k].hm2.lo = st[im][k].hm2.hi = PINF2;
            st[im][k].m2.lo  = st[im][k].m2.hi  = NINF2;
            st[im][k].m3.lo  = st[im][k].m3.hi  = NINF2;
            st[im][k].q1.lo  = st[im][k].q1.hi  = NINF2;
            st[im][k].q2.lo  = st[im][k].q2.hi  = NINF2;
            st[im][k].x1.lo  = st[im][k].x1.hi  = PINF2;
            st[im][k].x2.lo  = st[im][k].x2.hi  = PINF2;
            st[im][k].x3.lo  = st[im][k].x3.hi  = PINF2;
            st[im][k].xc.lo  = st[im][k].xc.hi  = PINF2;
        }

    const int y0 = r0 - 2 * K;
    Hp xn[2];
    #pragma unroll
    for (int im = 0; im < 2; ++im) {
        st[im][0].xc = load_row<FIRST, 1>(y0, c, f32src[im], bsrc[im]);
        xn[im]       = load_row<FIRST, 1>(y0 + 1, c, f32src[im], bsrc[im]);
    }

    // prologue edge write (consumed by first iteration after its barrier)
    #pragma unroll
    for (int im = 0; im < 2; ++im)
        #pragma unroll
        for (int k = 0; k < K; ++k)
            e2[im][k][t + 1] = make_uint2(
                as_u((h2){st[im][k].xc.lo[0], st[im][k].m2.lo[0]}),
                as_u((h2){st[im][k].xc.hi[1], st[im][k].m2.hi[1]}));

    float acc[4] = {0.f, 0.f, 0.f, 0.f};
    // Interior bands: every rm/em mask and load bound provably constant
    // (y in [r0-21, r0+81] within [0,1024) for r0 in [64, 896]).
    // unroll 4 = x-ring period: ring-shift copies vanish at back-edge.
    if (band >= 1 && band <= NBANDS - 2) {
        #pragma unroll 4
        for (int i = 0; i < NITER; ++i)
            iter_step<FIRST, LAST, 0>(y0 + i, t, c, r0, st, xn, f32src, bsrc, bdst, oth, acc, e2);
    } else {
        #pragma unroll 4
        for (int i = 0; i < NITER; ++i)
            iter_step<FIRST, LAST, 1>(y0 + i, t, c, r0, st, xn, f32src, bsrc, bdst, oth, acc, e2);
    }

    if constexpr (LAST) {                    // per-block partials (no atomics)
        double d[4] = {acc[0], acc[1], acc[2], acc[3]};
        for (int off = 32; off; off >>= 1) {
            #pragma unroll
            for (int j = 0; j < 4; ++j)
                d[j] += __shfl_down(d[j], off);
        }
        const int w = t >> 6;
        if ((t & 63) == 0) {
            #pragma unroll
            for (int j = 0; j < 4; ++j) lsum[j][w] = d[j];
        }
        __syncthreads();
        if (t == 0) {
            double s[4];
            #pragma unroll
            for (int j = 0; j < 4; ++j)
                s[j] = lsum[j][0] + lsum[j][1] + lsum[j][2] + lsum[j][3];
            int bid0 = z * NBANDS + band;              // pred-skel side
            int bid1 = (z + NIMG) * NBANDS + band;     // gt-skel side
            partials[2 * bid0]     = s[0];
            partials[2 * bid0 + 1] = s[1];
            partials[2 * bid1]     = s[2];
            partials[2 * bid1 + 1] = s[3];
        }
    }
}

__global__ __launch_bounds__(256) void finalize(
    const double* __restrict__ pp, float* __restrict__ out)
{
    __shared__ double sh[4][4];
    double i1 = 0, i2 = 0, t1 = 0, t2 = 0;
    for (int i = threadIdx.x; i < NPART; i += 256) {
        double a = pp[2 * i], b = pp[2 * i + 1];
        if (i < NIMG * NBANDS) { i1 += a; i2 += b; }   // z < 16: cl_pred side
        else                   { t1 += a; t2 += b; }   // z >= 16: skel_gt side
    }
    for (int off = 32; off; off >>= 1) {
        i1 += __shfl_down(i1, off); i2 += __shfl_down(i2, off);
        t1 += __shfl_down(t1, off); t2 += __shfl_down(t2, off);
    }
    const int w = threadIdx.x >> 6;
    if ((threadIdx.x & 63) == 0) { sh[0][w] = i1; sh[1][w] = i2; sh[2][w] = t1; sh[3][w] = t2; }
    __syncthreads();
    if (threadIdx.x == 0) {
        double s1 = 0, s2 = 0, s3 = 0, s4 = 0;
        for (int j = 0; j < 4; ++j) { s1 += sh[0][j]; s2 += sh[1][j]; s3 += sh[2][j]; s4 += sh[3][j]; }
        double iflat = (s1 + 1.0) / (s2 + 1.0);
        double tflat = (s3 + 1.0) / (s4 + 1.0);
        out[0] = (float)(1.0 - 2.0 * (iflat * tflat) / (iflat + tflat));
    }
}

extern "C" void kernel_launch(void* const* d_in, const int* in_sizes, int n_in,
                              void* d_out, int out_size, void* d_ws, size_t ws_size,
                              hipStream_t stream)
{
    const float* pred = (const float*)d_in[0];
    const float* gt   = (const float*)d_in[1];

    unsigned short* A = (unsigned short*)d_ws;            // 32 f16 images (64 MiB)
    unsigned short* B = A + (size_t)NZ * IMG_N;           // 32 f16 images
    double* partials  = (double*)d_ws;                    // overlaps A; A is dead
                                                          // when launch 5 (reads B) runs
    dim3 grid(NBANDS, NIMG);                              // 16 bands x 16 pairs

    skel<1, 0><<<grid, 256, 0, stream>>>(nullptr, A, pred, gt, nullptr);  // iters 1-4
    skel<0, 0><<<grid, 256, 0, stream>>>(A, B, pred, gt, nullptr);        // 5-8
    skel<0, 0><<<grid, 256, 0, stream>>>(B, A, pred, gt, nullptr);        // 9-12
    skel<0, 0><<<grid, 256, 0, stream>>>(A, B, pred, gt, nullptr);        // 13-16
    skel<0, 1><<<grid, 256, 0, stream>>>(B, nullptr, pred, gt, partials); // 17-20 + sums

    finalize<<<1, 256, 0, stream>>>(partials, (float*)d_out);
}